// Round 13
// baseline (286.962 us; speedup 1.0000x reference)
//
#include <hip/hip_runtime.h>
#include <hip/hip_bf16.h>
#include <hip/hip_fp16.h>

#define NEG_INF -3.4e38f
#define BCAP 9216   // per-bucket pair capacity (mean 8192, sd ~90 -> >11 sigma)

typedef _Float16 f16x8 __attribute__((ext_vector_type(8)));
typedef float f32x4 __attribute__((ext_vector_type(4)));

static __device__ __forceinline__ float leaky(float t) { return t >= 0.f ? t : 0.2f * t; }
static __device__ __forceinline__ float4 h4tof4(uint2 u) {
    float2 f01 = __half22float2(*(__half2*)&u.x);
    float2 f23 = __half22float2(*(__half2*)&u.y);
    return make_float4(f01.x, f01.y, f23.x, f23.y);
}

// ---------------------------------------------------------------------------
// P1: bucket edges by dst>>8. Packed pair: src (16b, N<65536) | dst_local<<16.
// Blocks 0..95 also transpose/cast W; block 96 initializes y = bf.
// ---------------------------------------------------------------------------
__global__ __launch_bounds__(256) void bucket_k(const int* __restrict__ eiA, const int* __restrict__ eiB,
                                                int E, int nbkt, int* __restrict__ bktCnt,
                                                int* __restrict__ pairs,
                                                const float* __restrict__ W0, const float* __restrict__ W1,
                                                const float* __restrict__ W2, _Float16* __restrict__ Wt,
                                                float* __restrict__ y, const float* __restrict__ bf, int G) {
    int t = threadIdx.x;
    if (blockIdx.x < 96) {   // fused weight transpose: Wt_l[c][k] = half(W_l[k][c])
        int i = blockIdx.x * 256 + t;
        int l = i >> 13;
        int idx = i & 8191;
        int c = idx >> 7;
        int k = idx & 127;
        const float* W = (l == 0) ? W0 : (l == 1) ? W1 : W2;
        Wt[i] = (_Float16)W[k * 64 + c];
    } else if (blockIdx.x == 96) {
        for (int g = t; g < G; g += 256) y[g] = bf[0];
    }

    int KB = gridDim.x >> 1;
    int b = blockIdx.x;
    int sel = (b >= KB);
    int bb = sel ? b - KB : b;
    const int* src = sel ? eiB : eiA;
    const int* dst = src + E;
    int* bc = bktCnt + (sel ? nbkt : 0);
    int* pr = pairs + (size_t)(sel ? nbkt : 0) * BCAP;

    __shared__ int hist[256];
    hist[t] = 0;
    __syncthreads();

    int e0 = (int)(((long long)bb * E) / KB);
    int e1 = (int)(((long long)(bb + 1) * E) / KB);
    for (int i = e0 + t; i < e1; i += 256) atomicAdd(&hist[dst[i] >> 8], 1);
    __syncthreads();

    int h = hist[t];
    int base = h ? atomicAdd(&bc[t], h) : 0;
    __syncthreads();
    hist[t] = base;
    __syncthreads();

    for (int i = e0 + t; i < e1; i += 256) {
        int d = dst[i];
        int s = src[i];
        int bk = d >> 8;
        int pos = atomicAdd(&hist[bk], 1);
        if (pos < BCAP) pr[(size_t)bk * BCAP + pos] = s | ((d & 255) << 16);
    }
}

// ---------------------------------------------------------------------------
// P2 (fused scan+scatter): per-bucket LDS histogram -> in-LDS inclusive scan
// -> bucket base via one global atomicAdd (ranges need only be disjoint) ->
// write rp2[node]=(r0,deg) -> scatter col with LDS cursors (pairs re-read is
// L2-hot, 32KB/bucket).
// ---------------------------------------------------------------------------
__global__ __launch_bounds__(256) void bscat_k(const int* __restrict__ bktCnt, const int* __restrict__ pairs,
                                               int N, int nbkt, int2* __restrict__ rp2,
                                               int* __restrict__ cursors,
                                               int* __restrict__ colA, int* __restrict__ colB) {
    __shared__ int h[256];
    __shared__ int sbase;
    int b = blockIdx.x;
    int sel = (b >= nbkt);
    int bk = sel ? b - nbkt : b;
    const int* bc = bktCnt + (sel ? nbkt : 0);
    const int* pr = pairs + ((size_t)(sel ? nbkt : 0) + bk) * BCAP;
    int* col = sel ? colB : colA;
    int t = threadIdx.x;
    h[t] = 0;
    __syncthreads();
    int cb = min(bc[bk], BCAP);
    for (int i = t; i < cb; i += 256) atomicAdd(&h[pr[i] >> 16], 1);
    __syncthreads();
    int v = h[t];
#pragma unroll
    for (int off = 1; off < 256; off <<= 1) {
        int add = (t >= off) ? h[t - off] : 0;
        __syncthreads();
        h[t] += add;
        __syncthreads();
    }
    if (t == 255) sbase = atomicAdd(&cursors[sel], h[255]);
    __syncthreads();
    int excl = h[t] - v + sbase;
    int node = (bk << 8) + t;
    if (node < N) rp2[(sel ? N : 0) + node] = make_int2(excl, v);
    __syncthreads();
    h[t] = excl;                      // reuse as running cursor
    __syncthreads();
    for (int i = t; i < cb; i += 256) {
        int pk = pr[i];
        int p = atomicAdd(&h[pk >> 16], 1);
        col[p] = pk & 0xFFFF;
    }
}

// ---------------------------------------------------------------------------
// MFMA GEMM: H16[N][64] = half(X[N][128] @ W[128][64]), LDS-free.
// Epilogue computes es/ed from f32 accumulators (16-lane shfl reduce).
// ---------------------------------------------------------------------------
template <int IN16>
__global__ __launch_bounds__(256) void gemm_k(const void* __restrict__ Xv, const _Float16* __restrict__ Wt,
                                              const float* __restrict__ asrc, const float* __restrict__ adst,
                                              _Float16* __restrict__ H16, float* __restrict__ es,
                                              float* __restrict__ ed, int N) {
    int tid = threadIdx.x;
    int w = tid >> 6;
    int lane = tid & 63;
    int l15 = lane & 15;
    int hi = lane >> 4;
    int rbase = blockIdx.x * 128 + w * 32;

    f32x4 acc[2][4] = {};
#pragma unroll
    for (int kc = 0; kc < 4; ++kc) {
        f16x8 a[2];
#pragma unroll
        for (int mt = 0; mt < 2; ++mt) {
            int r = min(rbase + mt * 16 + l15, N - 1);
            if (IN16) {
                const _Float16* X = (const _Float16*)Xv;
                a[mt] = *(const f16x8*)(X + (size_t)r * 128 + kc * 32 + hi * 8);
            } else {
                const float* px = (const float*)Xv + (size_t)r * 128 + kc * 32 + hi * 8;
                float4 x0 = *(const float4*)px;
                float4 x1 = *(const float4*)(px + 4);
                f16x8 t;
                t[0] = (_Float16)x0.x; t[1] = (_Float16)x0.y; t[2] = (_Float16)x0.z; t[3] = (_Float16)x0.w;
                t[4] = (_Float16)x1.x; t[5] = (_Float16)x1.y; t[6] = (_Float16)x1.z; t[7] = (_Float16)x1.w;
                a[mt] = t;
            }
        }
#pragma unroll
        for (int nt = 0; nt < 4; ++nt) {
            f16x8 bfrag = *(const f16x8*)(Wt + (size_t)(nt * 16 + l15) * 128 + kc * 32 + hi * 8);
            acc[0][nt] = __builtin_amdgcn_mfma_f32_16x16x32_f16(a[0], bfrag, acc[0][nt], 0, 0, 0);
            acc[1][nt] = __builtin_amdgcn_mfma_f32_16x16x32_f16(a[1], bfrag, acc[1][nt], 0, 0, 0);
        }
    }

    float av[4], dv[4];
#pragma unroll
    for (int nt = 0; nt < 4; ++nt) {
        av[nt] = asrc[nt * 16 + l15];
        dv[nt] = adst[nt * 16 + l15];
    }
#pragma unroll
    for (int mt = 0; mt < 2; ++mt) {
#pragma unroll
        for (int r = 0; r < 4; ++r) {
            int row = rbase + mt * 16 + hi * 4 + r;
            float s1 = 0.f, s2 = 0.f;
#pragma unroll
            for (int nt = 0; nt < 4; ++nt) {
                float v = acc[mt][nt][r];
                s1 += v * av[nt];
                s2 += v * dv[nt];
            }
#pragma unroll
            for (int off = 1; off < 16; off <<= 1) {
                s1 += __shfl_xor(s1, off, 64);
                s2 += __shfl_xor(s2, off, 64);
            }
            if (row < N) {
                if (l15 == 0) { es[row] = s1; ed[row] = s2; }
#pragma unroll
                for (int nt = 0; nt < 4; ++nt)
                    H16[(size_t)row * 64 + nt * 16 + l15] = (_Float16)acc[mt][nt][r];
            }
        }
    }
}

// ---------------------------------------------------------------------------
// Fused GAT aggregation (r10 structure, gather deepened to 32 entries/iter =
// 8 uint2 row-loads in flight per lane). One wave, BOTH edge sets per node.
// Self-shift softmax (no max pass). f32 accum. No barriers (per-wave LDS).
// ---------------------------------------------------------------------------
template <int WRITEY>
__global__ __launch_bounds__(256) void agg_k(const _Float16* __restrict__ h16,
                                             const float* __restrict__ es, const float* __restrict__ ed,
                                             const int2* __restrict__ rp2A, const int* __restrict__ colA,
                                             const int2* __restrict__ rp2B, const int* __restrict__ colB,
                                             const float* __restrict__ bias, __half* __restrict__ xout, int N,
                                             const float* __restrict__ Wf, float* __restrict__ ydot) {
    __shared__ int2 sp[4][2][64];
    int w = threadIdx.x >> 6;
    int lane = threadIdx.x & 63;
    int wid = blockIdx.x * 4 + w;
    if (wid >= N) return;
    int q = lane >> 4;
    int l16 = lane & 15;
    int2 ra = rp2A[wid];
    int2 rb = rp2B[wid];
    float edv = ed[wid];
    float m = leaky(es[wid] + edv);
    const char* hb = (const char*)h16;
    int loff = l16 * 8;

    // self row (shared), p = exp(0) = 1, counted by quarter 0 only
    uint2 hs = *(const uint2*)(hb + (((size_t)wid) << 7) + loff);
    float4 fs = h4tof4(hs);
    float s0 = (q == 0) ? 1.f : 0.f;
    float4 accA = make_float4(s0 * fs.x, s0 * fs.y, s0 * fs.z, s0 * fs.w);
    float4 accB = accA;
    float zA = s0, zB = s0;

#define GATHER32(SPW, ACC, ZV, RR)                                           \
    for (int j = 0; j < (RR); j += 32) {                                     \
        int2 e1 = (SPW)[j + q];                                              \
        int2 e2 = (SPW)[j + 4 + q];                                          \
        int2 e3 = (SPW)[j + 8 + q];                                          \
        int2 e4 = (SPW)[j + 12 + q];                                         \
        int2 e5 = (SPW)[j + 16 + q];                                         \
        int2 e6 = (SPW)[j + 20 + q];                                         \
        int2 e7 = (SPW)[j + 24 + q];                                         \
        int2 e8 = (SPW)[j + 28 + q];                                         \
        uint2 u1 = *(const uint2*)(hb + (unsigned)(e1.x + loff));            \
        uint2 u2 = *(const uint2*)(hb + (unsigned)(e2.x + loff));            \
        uint2 u3 = *(const uint2*)(hb + (unsigned)(e3.x + loff));            \
        uint2 u4 = *(const uint2*)(hb + (unsigned)(e4.x + loff));            \
        uint2 u5 = *(const uint2*)(hb + (unsigned)(e5.x + loff));            \
        uint2 u6 = *(const uint2*)(hb + (unsigned)(e6.x + loff));            \
        uint2 u7 = *(const uint2*)(hb + (unsigned)(e7.x + loff));            \
        uint2 u8 = *(const uint2*)(hb + (unsigned)(e8.x + loff));            \
        float p1 = __int_as_float(e1.y), p2 = __int_as_float(e2.y);          \
        float p3 = __int_as_float(e3.y), p4 = __int_as_float(e4.y);          \
        float p5 = __int_as_float(e5.y), p6 = __int_as_float(e6.y);          \
        float p7 = __int_as_float(e7.y), p8 = __int_as_float(e8.y);          \
        float4 f1 = h4tof4(u1), f2 = h4tof4(u2), f3 = h4tof4(u3), f4 = h4tof4(u4); \
        float4 f5 = h4tof4(u5), f6 = h4tof4(u6), f7 = h4tof4(u7), f8 = h4tof4(u8); \
        ZV += ((p1 + p2) + (p3 + p4)) + ((p5 + p6) + (p7 + p8));             \
        ACC.x = fmaf(p1, f1.x, ACC.x); ACC.y = fmaf(p1, f1.y, ACC.y);        \
        ACC.z = fmaf(p1, f1.z, ACC.z); ACC.w = fmaf(p1, f1.w, ACC.w);        \
        ACC.x = fmaf(p2, f2.x, ACC.x); ACC.y = fmaf(p2, f2.y, ACC.y);        \
        ACC.z = fmaf(p2, f2.z, ACC.z); ACC.w = fmaf(p2, f2.w, ACC.w);        \
        ACC.x = fmaf(p3, f3.x, ACC.x); ACC.y = fmaf(p3, f3.y, ACC.y);        \
        ACC.z = fmaf(p3, f3.z, ACC.z); ACC.w = fmaf(p3, f3.w, ACC.w);        \
        ACC.x = fmaf(p4, f4.x, ACC.x); ACC.y = fmaf(p4, f4.y, ACC.y);        \
        ACC.z = fmaf(p4, f4.z, ACC.z); ACC.w = fmaf(p4, f4.w, ACC.w);        \
        ACC.x = fmaf(p5, f5.x, ACC.x); ACC.y = fmaf(p5, f5.y, ACC.y);        \
        ACC.z = fmaf(p5, f5.z, ACC.z); ACC.w = fmaf(p5, f5.w, ACC.w);        \
        ACC.x = fmaf(p6, f6.x, ACC.x); ACC.y = fmaf(p6, f6.y, ACC.y);        \
        ACC.z = fmaf(p6, f6.z, ACC.z); ACC.w = fmaf(p6, f6.w, ACC.w);        \
        ACC.x = fmaf(p7, f7.x, ACC.x); ACC.y = fmaf(p7, f7.y, ACC.y);        \
        ACC.z = fmaf(p7, f7.z, ACC.z); ACC.w = fmaf(p7, f7.w, ACC.w);        \
        ACC.x = fmaf(p8, f8.x, ACC.x); ACC.y = fmaf(p8, f8.y, ACC.y);        \
        ACC.z = fmaf(p8, f8.z, ACC.z); ACC.w = fmaf(p8, f8.w, ACC.w);        \
    }

    if (ra.y <= 64 && rb.y <= 64) {
        // stage both sets (independent chains overlap)
        int svA = (lane < ra.y) ? colA[ra.x + lane] : wid;
        int svB = (lane < rb.y) ? colB[rb.x + lane] : wid;
        float eA = es[svA];
        float eB = es[svB];
        float pA = (lane < ra.y) ? __expf(leaky(eA + edv) - m) : 0.f;
        float pB = (lane < rb.y) ? __expf(leaky(eB + edv) - m) : 0.f;
        sp[w][0][lane] = make_int2(svA << 7, __float_as_int(pA));
        sp[w][1][lane] = make_int2(svB << 7, __float_as_int(pB));
        int rrA = ((ra.y + 31) >> 5) << 5;
        int rrB = ((rb.y + 31) >> 5) << 5;
        GATHER32(sp[w][0], accA, zA, rrA)
        GATHER32(sp[w][1], accB, zB, rrB)
    } else {
        for (int base = 0; base < ra.y; base += 64) {
            int vi = base + lane;
            int sv = (vi < ra.y) ? colA[ra.x + vi] : wid;
            float e = es[sv];
            float p = (vi < ra.y) ? __expf(leaky(e + edv) - m) : 0.f;
            sp[w][0][lane] = make_int2(sv << 7, __float_as_int(p));
            int cw = min(64, ra.y - base);
            int rr = ((cw + 31) >> 5) << 5;
            GATHER32(sp[w][0], accA, zA, rr)
        }
        for (int base = 0; base < rb.y; base += 64) {
            int vi = base + lane;
            int sv = (vi < rb.y) ? colB[rb.x + vi] : wid;
            float e = es[sv];
            float p = (vi < rb.y) ? __expf(leaky(e + edv) - m) : 0.f;
            sp[w][1][lane] = make_int2(sv << 7, __float_as_int(p));
            int cw = min(64, rb.y - base);
            int rr = ((cw + 31) >> 5) << 5;
            GATHER32(sp[w][1], accB, zB, rr)
        }
    }
#undef GATHER32

    // cross-quarter reductions (within a quarter all lanes identical z)
    zA += __shfl_xor(zA, 16, 64); zA += __shfl_xor(zA, 32, 64);
    zB += __shfl_xor(zB, 16, 64); zB += __shfl_xor(zB, 32, 64);
    accA.x += __shfl_xor(accA.x, 16, 64); accA.x += __shfl_xor(accA.x, 32, 64);
    accA.y += __shfl_xor(accA.y, 16, 64); accA.y += __shfl_xor(accA.y, 32, 64);
    accA.z += __shfl_xor(accA.z, 16, 64); accA.z += __shfl_xor(accA.z, 32, 64);
    accA.w += __shfl_xor(accA.w, 16, 64); accA.w += __shfl_xor(accA.w, 32, 64);
    accB.x += __shfl_xor(accB.x, 16, 64); accB.x += __shfl_xor(accB.x, 32, 64);
    accB.y += __shfl_xor(accB.y, 16, 64); accB.y += __shfl_xor(accB.y, 32, 64);
    accB.z += __shfl_xor(accB.z, 16, 64); accB.z += __shfl_xor(accB.z, 32, 64);
    accB.w += __shfl_xor(accB.w, 16, 64); accB.w += __shfl_xor(accB.w, 32, 64);

    if (q == 0) {
        float invA = 1.f / (zA + 1e-16f);
        float invB = 1.f / (zB + 1e-16f);
        float4 b4 = *(const float4*)(bias + l16 * 4);
        float4 oA, oB;
        oA.x = fmaxf(accA.x * invA + b4.x, 0.f);
        oA.y = fmaxf(accA.y * invA + b4.y, 0.f);
        oA.z = fmaxf(accA.z * invA + b4.z, 0.f);
        oA.w = fmaxf(accA.w * invA + b4.w, 0.f);
        oB.x = fmaxf(accB.x * invB + b4.x, 0.f);
        oB.y = fmaxf(accB.y * invB + b4.y, 0.f);
        oB.z = fmaxf(accB.z * invB + b4.z, 0.f);
        oB.w = fmaxf(accB.w * invB + b4.w, 0.f);
        if (!WRITEY) {
            __half2 a01 = __floats2half2_rn(oA.x, oA.y);
            __half2 a23 = __floats2half2_rn(oA.z, oA.w);
            __half2 b01 = __floats2half2_rn(oB.x, oB.y);
            __half2 b23 = __floats2half2_rn(oB.z, oB.w);
            uint2 stA, stB;
            stA.x = *(unsigned*)&a01; stA.y = *(unsigned*)&a23;
            stB.x = *(unsigned*)&b01; stB.y = *(unsigned*)&b23;
            *(uint2*)(xout + (size_t)wid * 128 + l16 * 4) = stA;
            *(uint2*)(xout + (size_t)wid * 128 + 64 + l16 * 4) = stB;
        } else {
            float4 wA = *(const float4*)(Wf + l16 * 4);
            float4 wB = *(const float4*)(Wf + 64 + l16 * 4);
            float hd = oA.x * wA.x + oA.y * wA.y + oA.z * wA.z + oA.w * wA.w
                     + oB.x * wB.x + oB.y * wB.y + oB.z * wB.z + oB.w * wB.w;
            hd += __shfl_xor(hd, 1, 64);
            hd += __shfl_xor(hd, 2, 64);
            hd += __shfl_xor(hd, 4, 64);
            hd += __shfl_xor(hd, 8, 64);
            if (l16 == 0) ydot[wid] = hd;
        }
    }
}

// ---------------------------------------------------------------------------
// Tiny pool: y[g] += sum_n ydot[n]; batch sorted.
// ---------------------------------------------------------------------------
__global__ __launch_bounds__(256) void pool3_k(const float* __restrict__ ydot,
                                               const int* __restrict__ batch, float* __restrict__ y,
                                               int N, int G) {
    __shared__ float gacc[512];
    int t = threadIdx.x;
    if (G <= 512) {
        for (int g = t; g < 512; g += 256) gacc[g] = 0.f;
        __syncthreads();
        int n0 = blockIdx.x * 2048 + t * 8;
        int curg = -1;
        float accv = 0.f;
        for (int i = 0; i < 8; ++i) {
            int n = n0 + i;
            if (n < N) {
                float v = ydot[n];
                int g = batch[n];
                if (g == curg) accv += v;
                else {
                    if (curg >= 0) atomicAdd(&gacc[curg], accv);
                    curg = g;
                    accv = v;
                }
            }
        }
        if (curg >= 0) atomicAdd(&gacc[curg], accv);
        __syncthreads();
        for (int g = t; g < G; g += 256) {
            float v = gacc[g];
            if (v != 0.f) atomicAdd(&y[g], v);
        }
    } else {
        int n0 = blockIdx.x * 2048 + t * 8;
        for (int i = 0; i < 8; ++i) {
            int n = n0 + i;
            if (n < N) atomicAdd(&y[batch[n]], ydot[n]);
        }
    }
}

// ---------------------------------------------------------------------------
// Launch
// ---------------------------------------------------------------------------
static inline size_t align256(size_t x) { return (x + 255) & ~(size_t)255; }

extern "C" void kernel_launch(void* const* d_in, const int* in_sizes, int n_in,
                              void* d_out, int out_size, void* d_ws, size_t ws_size,
                              hipStream_t stream) {
    const float* x0    = (const float*)d_in[0];
    const int*   eiA   = (const int*)d_in[1];
    const int*   eiB   = (const int*)d_in[2];
    const int*   batch = (const int*)d_in[3];
    const float* W[3]   = {(const float*)d_in[4],  (const float*)d_in[8],  (const float*)d_in[12]};
    const float* as_[3] = {(const float*)d_in[5],  (const float*)d_in[9],  (const float*)d_in[13]};
    const float* ad_[3] = {(const float*)d_in[6],  (const float*)d_in[10], (const float*)d_in[14]};
    const float* bb[3]  = {(const float*)d_in[7],  (const float*)d_in[11], (const float*)d_in[15]};
    const float* Wf = (const float*)d_in[16];
    const float* bf = (const float*)d_in[17];

    const int N = in_sizes[0] / 128;   // 50000 (< 65536: packed-pair assumption)
    const int E = in_sizes[1] / 2;
    const int G = out_size;
    float* y = (float*)d_out;

    const int nbkt = (N + 255) >> 8;

    char* p = (char*)d_ws;
    int2* rp2   = (int2*)p; p += align256((size_t)2 * N * 8);
    int* bktCnt = (int*)p;  p += align256((size_t)2 * nbkt * 4);
    int* cursors = (int*)p; p += 256;      // adjacent to bktCnt; zeroed by same memset
    int* colA   = (int*)p;  p += align256((size_t)E * 4);
    int* colB   = (int*)p;  p += align256((size_t)E * 4);
    _Float16* h16 = (_Float16*)p; p += align256((size_t)N * 64 * 2);
    float* es   = (float*)p; p += align256((size_t)N * 4);
    float* ed   = (float*)p; p += align256((size_t)N * 4);
    float* ydot = (float*)p; p += align256((size_t)N * 4);
    _Float16* Wt = (_Float16*)p; p += align256((size_t)3 * 8192 * 2);
    __half* xb0 = (__half*)p; p += align256((size_t)N * 128 * 2);
    __half* xb1 = (__half*)p; p += align256((size_t)N * 128 * 2);
    int* pairs = (int*)xb0;   // 2*nbkt*BCAP*4 ~ 14.5MB aliases xb0+xb1 (dead then)
    (void)ws_size; (void)n_in;

    const int KB = 256;
    const int WB = (N + 3) / 4;
    const int PB3 = (N + 2047) / 2048;

    // ---- CSR build via bucket sort (+fused W transpose, y init) ----
    hipMemsetAsync(bktCnt, 0, align256((size_t)2 * nbkt * 4) + 256, stream);
    bucket_k<<<2 * KB, 256, 0, stream>>>(eiA, eiB, E, nbkt, bktCnt, pairs, W[0], W[1], W[2], Wt, y, bf, G);
    bscat_k<<<2 * nbkt, 256, 0, stream>>>(bktCnt, pairs, N, nbkt, rp2, cursors, colA, colB);

    // ---- 3 GAT layers; weights shared between branches A and B ----
    const int GB = (N + 127) / 128;
    const int2* rp2A = rp2;
    const int2* rp2B = rp2 + N;
    gemm_k<0><<<GB, 256, 0, stream>>>(x0, Wt, as_[0], ad_[0], h16, es, ed, N);
    agg_k<0><<<WB, 256, 0, stream>>>(h16, es, ed, rp2A, colA, rp2B, colB, bb[0], xb0, N, Wf, ydot);
    gemm_k<1><<<GB, 256, 0, stream>>>(xb0, Wt + 8192, as_[1], ad_[1], h16, es, ed, N);
    agg_k<0><<<WB, 256, 0, stream>>>(h16, es, ed, rp2A, colA, rp2B, colB, bb[1], xb1, N, Wf, ydot);
    gemm_k<1><<<GB, 256, 0, stream>>>(xb1, Wt + 16384, as_[2], ad_[2], h16, es, ed, N);
    agg_k<1><<<WB, 256, 0, stream>>>(h16, es, ed, rp2A, colA, rp2B, colB, bb[2], (__half*)nullptr, N, Wf, ydot);

    // ---- tiny pool over ydot ----
    pool3_k<<<PB3, 256, 0, stream>>>(ydot, batch, y, N, G);
}

// Round 14
// 272.831 us; speedup vs baseline: 1.0518x; 1.0518x over previous
//
#include <hip/hip_runtime.h>
#include <hip/hip_bf16.h>
#include <hip/hip_fp16.h>

#define NEG_INF -3.4e38f
#define BCAP 9216   // per-bucket pair capacity (mean 8192, sd ~90 -> >11 sigma)

typedef _Float16 f16x8 __attribute__((ext_vector_type(8)));
typedef float f32x4 __attribute__((ext_vector_type(4)));

static __device__ __forceinline__ float leaky(float t) { return t >= 0.f ? t : 0.2f * t; }
static __device__ __forceinline__ float4 h4tof4(uint2 u) {
    float2 f01 = __half22float2(*(__half2*)&u.x);
    float2 f23 = __half22float2(*(__half2*)&u.y);
    return make_float4(f01.x, f01.y, f23.x, f23.y);
}

// ---------------------------------------------------------------------------
// P1: bucket edges by dst>>8. Packed pair: src (16b, N<65536) | dst_local<<16.
// Blocks 0..95 also transpose/cast W; block 96 initializes y = bf.
// ---------------------------------------------------------------------------
__global__ __launch_bounds__(256) void bucket_k(const int* __restrict__ eiA, const int* __restrict__ eiB,
                                                int E, int nbkt, int* __restrict__ bktCnt,
                                                int* __restrict__ pairs,
                                                const float* __restrict__ W0, const float* __restrict__ W1,
                                                const float* __restrict__ W2, _Float16* __restrict__ Wt,
                                                float* __restrict__ y, const float* __restrict__ bf, int G) {
    int t = threadIdx.x;
    if (blockIdx.x < 96) {   // fused weight transpose: Wt_l[c][k] = half(W_l[k][c])
        int i = blockIdx.x * 256 + t;
        int l = i >> 13;
        int idx = i & 8191;
        int c = idx >> 7;
        int k = idx & 127;
        const float* W = (l == 0) ? W0 : (l == 1) ? W1 : W2;
        Wt[i] = (_Float16)W[k * 64 + c];
    } else if (blockIdx.x == 96) {
        for (int g = t; g < G; g += 256) y[g] = bf[0];
    }

    int KB = gridDim.x >> 1;
    int b = blockIdx.x;
    int sel = (b >= KB);
    int bb = sel ? b - KB : b;
    const int* src = sel ? eiB : eiA;
    const int* dst = src + E;
    int* bc = bktCnt + (sel ? nbkt : 0);
    int* pr = pairs + (size_t)(sel ? nbkt : 0) * BCAP;

    __shared__ int hist[256];
    hist[t] = 0;
    __syncthreads();

    int e0 = (int)(((long long)bb * E) / KB);
    int e1 = (int)(((long long)(bb + 1) * E) / KB);
    for (int i = e0 + t; i < e1; i += 256) atomicAdd(&hist[dst[i] >> 8], 1);
    __syncthreads();

    int h = hist[t];
    int base = h ? atomicAdd(&bc[t], h) : 0;
    __syncthreads();
    hist[t] = base;
    __syncthreads();

    for (int i = e0 + t; i < e1; i += 256) {
        int d = dst[i];
        int s = src[i];
        int bk = d >> 8;
        int pos = atomicAdd(&hist[bk], 1);
        if (pos < BCAP) pr[(size_t)bk * BCAP + pos] = s | ((d & 255) << 16);
    }
}

// ---------------------------------------------------------------------------
// P2 (fused scan+scatter): per-bucket LDS histogram -> in-LDS inclusive scan
// -> bucket base via one global atomicAdd (ranges need only be disjoint) ->
// write rp2[node]=(r0,deg) -> scatter col with LDS cursors (pairs re-read is
// L2-hot, 32KB/bucket).
// ---------------------------------------------------------------------------
__global__ __launch_bounds__(256) void bscat_k(const int* __restrict__ bktCnt, const int* __restrict__ pairs,
                                               int N, int nbkt, int2* __restrict__ rp2,
                                               int* __restrict__ cursors,
                                               int* __restrict__ colA, int* __restrict__ colB) {
    __shared__ int h[256];
    __shared__ int sbase;
    int b = blockIdx.x;
    int sel = (b >= nbkt);
    int bk = sel ? b - nbkt : b;
    const int* bc = bktCnt + (sel ? nbkt : 0);
    const int* pr = pairs + ((size_t)(sel ? nbkt : 0) + bk) * BCAP;
    int* col = sel ? colB : colA;
    int t = threadIdx.x;
    h[t] = 0;
    __syncthreads();
    int cb = min(bc[bk], BCAP);
    for (int i = t; i < cb; i += 256) atomicAdd(&h[pr[i] >> 16], 1);
    __syncthreads();
    int v = h[t];
#pragma unroll
    for (int off = 1; off < 256; off <<= 1) {
        int add = (t >= off) ? h[t - off] : 0;
        __syncthreads();
        h[t] += add;
        __syncthreads();
    }
    if (t == 255) sbase = atomicAdd(&cursors[sel], h[255]);
    __syncthreads();
    int excl = h[t] - v + sbase;
    int node = (bk << 8) + t;
    if (node < N) rp2[(sel ? N : 0) + node] = make_int2(excl, v);
    __syncthreads();
    h[t] = excl;                      // reuse as running cursor
    __syncthreads();
    for (int i = t; i < cb; i += 256) {
        int pk = pr[i];
        int p = atomicAdd(&h[pk >> 16], 1);
        col[p] = pk & 0xFFFF;
    }
}

// ---------------------------------------------------------------------------
// MFMA GEMM: H16[N][64] = half(X[N][128] @ W[128][64]), LDS-free.
// Epilogue computes es/ed from f32 accumulators (16-lane shfl reduce).
// ---------------------------------------------------------------------------
template <int IN16>
__global__ __launch_bounds__(256) void gemm_k(const void* __restrict__ Xv, const _Float16* __restrict__ Wt,
                                              const float* __restrict__ asrc, const float* __restrict__ adst,
                                              _Float16* __restrict__ H16, float* __restrict__ es,
                                              float* __restrict__ ed, int N) {
    int tid = threadIdx.x;
    int w = tid >> 6;
    int lane = tid & 63;
    int l15 = lane & 15;
    int hi = lane >> 4;
    int rbase = blockIdx.x * 128 + w * 32;

    f32x4 acc[2][4] = {};
#pragma unroll
    for (int kc = 0; kc < 4; ++kc) {
        f16x8 a[2];
#pragma unroll
        for (int mt = 0; mt < 2; ++mt) {
            int r = min(rbase + mt * 16 + l15, N - 1);
            if (IN16) {
                const _Float16* X = (const _Float16*)Xv;
                a[mt] = *(const f16x8*)(X + (size_t)r * 128 + kc * 32 + hi * 8);
            } else {
                const float* px = (const float*)Xv + (size_t)r * 128 + kc * 32 + hi * 8;
                float4 x0 = *(const float4*)px;
                float4 x1 = *(const float4*)(px + 4);
                f16x8 t;
                t[0] = (_Float16)x0.x; t[1] = (_Float16)x0.y; t[2] = (_Float16)x0.z; t[3] = (_Float16)x0.w;
                t[4] = (_Float16)x1.x; t[5] = (_Float16)x1.y; t[6] = (_Float16)x1.z; t[7] = (_Float16)x1.w;
                a[mt] = t;
            }
        }
#pragma unroll
        for (int nt = 0; nt < 4; ++nt) {
            f16x8 bfrag = *(const f16x8*)(Wt + (size_t)(nt * 16 + l15) * 128 + kc * 32 + hi * 8);
            acc[0][nt] = __builtin_amdgcn_mfma_f32_16x16x32_f16(a[0], bfrag, acc[0][nt], 0, 0, 0);
            acc[1][nt] = __builtin_amdgcn_mfma_f32_16x16x32_f16(a[1], bfrag, acc[1][nt], 0, 0, 0);
        }
    }

    float av[4], dv[4];
#pragma unroll
    for (int nt = 0; nt < 4; ++nt) {
        av[nt] = asrc[nt * 16 + l15];
        dv[nt] = adst[nt * 16 + l15];
    }
#pragma unroll
    for (int mt = 0; mt < 2; ++mt) {
#pragma unroll
        for (int r = 0; r < 4; ++r) {
            int row = rbase + mt * 16 + hi * 4 + r;
            float s1 = 0.f, s2 = 0.f;
#pragma unroll
            for (int nt = 0; nt < 4; ++nt) {
                float v = acc[mt][nt][r];
                s1 += v * av[nt];
                s2 += v * dv[nt];
            }
#pragma unroll
            for (int off = 1; off < 16; off <<= 1) {
                s1 += __shfl_xor(s1, off, 64);
                s2 += __shfl_xor(s2, off, 64);
            }
            if (row < N) {
                if (l15 == 0) { es[row] = s1; ed[row] = s2; }
#pragma unroll
                for (int nt = 0; nt < 4; ++nt)
                    H16[(size_t)row * 64 + nt * 16 + l15] = (_Float16)acc[mt][nt][r];
            }
        }
    }
}

// ---------------------------------------------------------------------------
// Fused GAT aggregation (r10/r12 structure — measured best: 57.5us, VGPR 28).
// One wave, BOTH edge sets for one dst node (shared es/ed/m/self-row; the two
// prologue chains overlap). Self-shift softmax (shift-invariant; no max pass).
// Per-set staged gather, 16 entries/iter (4 uint2 loads in flight per lane).
// f32 accum. No barriers (per-wave LDS).
// ---------------------------------------------------------------------------
template <int WRITEY>
__global__ __launch_bounds__(256) void agg_k(const _Float16* __restrict__ h16,
                                             const float* __restrict__ es, const float* __restrict__ ed,
                                             const int2* __restrict__ rp2A, const int* __restrict__ colA,
                                             const int2* __restrict__ rp2B, const int* __restrict__ colB,
                                             const float* __restrict__ bias, __half* __restrict__ xout, int N,
                                             const float* __restrict__ Wf, float* __restrict__ ydot) {
    __shared__ int2 sp[4][2][64];
    int w = threadIdx.x >> 6;
    int lane = threadIdx.x & 63;
    int wid = blockIdx.x * 4 + w;
    if (wid >= N) return;
    int q = lane >> 4;
    int l16 = lane & 15;
    int2 ra = rp2A[wid];
    int2 rb = rp2B[wid];
    float edv = ed[wid];
    float m = leaky(es[wid] + edv);
    const char* hb = (const char*)h16;
    int loff = l16 * 8;

    // self row (shared), p = exp(0) = 1, counted by quarter 0 only
    uint2 hs = *(const uint2*)(hb + (((size_t)wid) << 7) + loff);
    float4 fs = h4tof4(hs);
    float s0 = (q == 0) ? 1.f : 0.f;
    float4 accA = make_float4(s0 * fs.x, s0 * fs.y, s0 * fs.z, s0 * fs.w);
    float4 accB = accA;
    float zA = s0, zB = s0;

#define GATHER16(SPW, ACC, ZV, RR)                                           \
    for (int j = 0; j < (RR); j += 16) {                                     \
        int2 e1 = (SPW)[j + q];                                              \
        int2 e2 = (SPW)[j + 4 + q];                                          \
        int2 e3 = (SPW)[j + 8 + q];                                          \
        int2 e4 = (SPW)[j + 12 + q];                                         \
        uint2 u1 = *(const uint2*)(hb + (unsigned)(e1.x + loff));            \
        uint2 u2 = *(const uint2*)(hb + (unsigned)(e2.x + loff));            \
        uint2 u3 = *(const uint2*)(hb + (unsigned)(e3.x + loff));            \
        uint2 u4 = *(const uint2*)(hb + (unsigned)(e4.x + loff));            \
        float p1 = __int_as_float(e1.y), p2 = __int_as_float(e2.y);          \
        float p3 = __int_as_float(e3.y), p4 = __int_as_float(e4.y);          \
        float4 f1 = h4tof4(u1), f2 = h4tof4(u2), f3 = h4tof4(u3), f4 = h4tof4(u4); \
        ZV += (p1 + p2) + (p3 + p4);                                         \
        ACC.x = fmaf(p1, f1.x, ACC.x); ACC.y = fmaf(p1, f1.y, ACC.y);        \
        ACC.z = fmaf(p1, f1.z, ACC.z); ACC.w = fmaf(p1, f1.w, ACC.w);        \
        ACC.x = fmaf(p2, f2.x, ACC.x); ACC.y = fmaf(p2, f2.y, ACC.y);        \
        ACC.z = fmaf(p2, f2.z, ACC.z); ACC.w = fmaf(p2, f2.w, ACC.w);        \
        ACC.x = fmaf(p3, f3.x, ACC.x); ACC.y = fmaf(p3, f3.y, ACC.y);        \
        ACC.z = fmaf(p3, f3.z, ACC.z); ACC.w = fmaf(p3, f3.w, ACC.w);        \
        ACC.x = fmaf(p4, f4.x, ACC.x); ACC.y = fmaf(p4, f4.y, ACC.y);        \
        ACC.z = fmaf(p4, f4.z, ACC.z); ACC.w = fmaf(p4, f4.w, ACC.w);        \
    }

    if (ra.y <= 64 && rb.y <= 64) {
        // stage both sets (independent chains overlap)
        int svA = (lane < ra.y) ? colA[ra.x + lane] : wid;
        int svB = (lane < rb.y) ? colB[rb.x + lane] : wid;
        float eA = es[svA];
        float eB = es[svB];
        float pA = (lane < ra.y) ? __expf(leaky(eA + edv) - m) : 0.f;
        float pB = (lane < rb.y) ? __expf(leaky(eB + edv) - m) : 0.f;
        sp[w][0][lane] = make_int2(svA << 7, __float_as_int(pA));
        sp[w][1][lane] = make_int2(svB << 7, __float_as_int(pB));
        int rrA = ((ra.y + 15) >> 4) << 4;
        int rrB = ((rb.y + 15) >> 4) << 4;
        GATHER16(sp[w][0], accA, zA, rrA)
        GATHER16(sp[w][1], accB, zB, rrB)
    } else {
        for (int base = 0; base < ra.y; base += 64) {
            int vi = base + lane;
            int sv = (vi < ra.y) ? colA[ra.x + vi] : wid;
            float e = es[sv];
            float p = (vi < ra.y) ? __expf(leaky(e + edv) - m) : 0.f;
            sp[w][0][lane] = make_int2(sv << 7, __float_as_int(p));
            int cw = min(64, ra.y - base);
            int rr = ((cw + 15) >> 4) << 4;
            GATHER16(sp[w][0], accA, zA, rr)
        }
        for (int base = 0; base < rb.y; base += 64) {
            int vi = base + lane;
            int sv = (vi < rb.y) ? colB[rb.x + vi] : wid;
            float e = es[sv];
            float p = (vi < rb.y) ? __expf(leaky(e + edv) - m) : 0.f;
            sp[w][1][lane] = make_int2(sv << 7, __float_as_int(p));
            int cw = min(64, rb.y - base);
            int rr = ((cw + 15) >> 4) << 4;
            GATHER16(sp[w][1], accB, zB, rr)
        }
    }
#undef GATHER16

    // cross-quarter reductions (within a quarter all lanes identical z)
    zA += __shfl_xor(zA, 16, 64); zA += __shfl_xor(zA, 32, 64);
    zB += __shfl_xor(zB, 16, 64); zB += __shfl_xor(zB, 32, 64);
    accA.x += __shfl_xor(accA.x, 16, 64); accA.x += __shfl_xor(accA.x, 32, 64);
    accA.y += __shfl_xor(accA.y, 16, 64); accA.y += __shfl_xor(accA.y, 32, 64);
    accA.z += __shfl_xor(accA.z, 16, 64); accA.z += __shfl_xor(accA.z, 32, 64);
    accA.w += __shfl_xor(accA.w, 16, 64); accA.w += __shfl_xor(accA.w, 32, 64);
    accB.x += __shfl_xor(accB.x, 16, 64); accB.x += __shfl_xor(accB.x, 32, 64);
    accB.y += __shfl_xor(accB.y, 16, 64); accB.y += __shfl_xor(accB.y, 32, 64);
    accB.z += __shfl_xor(accB.z, 16, 64); accB.z += __shfl_xor(accB.z, 32, 64);
    accB.w += __shfl_xor(accB.w, 16, 64); accB.w += __shfl_xor(accB.w, 32, 64);

    if (q == 0) {
        float invA = 1.f / (zA + 1e-16f);
        float invB = 1.f / (zB + 1e-16f);
        float4 b4 = *(const float4*)(bias + l16 * 4);
        float4 oA, oB;
        oA.x = fmaxf(accA.x * invA + b4.x, 0.f);
        oA.y = fmaxf(accA.y * invA + b4.y, 0.f);
        oA.z = fmaxf(accA.z * invA + b4.z, 0.f);
        oA.w = fmaxf(accA.w * invA + b4.w, 0.f);
        oB.x = fmaxf(accB.x * invB + b4.x, 0.f);
        oB.y = fmaxf(accB.y * invB + b4.y, 0.f);
        oB.z = fmaxf(accB.z * invB + b4.z, 0.f);
        oB.w = fmaxf(accB.w * invB + b4.w, 0.f);
        if (!WRITEY) {
            __half2 a01 = __floats2half2_rn(oA.x, oA.y);
            __half2 a23 = __floats2half2_rn(oA.z, oA.w);
            __half2 b01 = __floats2half2_rn(oB.x, oB.y);
            __half2 b23 = __floats2half2_rn(oB.z, oB.w);
            uint2 stA, stB;
            stA.x = *(unsigned*)&a01; stA.y = *(unsigned*)&a23;
            stB.x = *(unsigned*)&b01; stB.y = *(unsigned*)&b23;
            *(uint2*)(xout + (size_t)wid * 128 + l16 * 4) = stA;
            *(uint2*)(xout + (size_t)wid * 128 + 64 + l16 * 4) = stB;
        } else {
            float4 wA = *(const float4*)(Wf + l16 * 4);
            float4 wB = *(const float4*)(Wf + 64 + l16 * 4);
            float hd = oA.x * wA.x + oA.y * wA.y + oA.z * wA.z + oA.w * wA.w
                     + oB.x * wB.x + oB.y * wB.y + oB.z * wB.z + oB.w * wB.w;
            hd += __shfl_xor(hd, 1, 64);
            hd += __shfl_xor(hd, 2, 64);
            hd += __shfl_xor(hd, 4, 64);
            hd += __shfl_xor(hd, 8, 64);
            if (l16 == 0) ydot[wid] = hd;
        }
    }
}

// ---------------------------------------------------------------------------
// Tiny pool: y[g] += sum_n ydot[n]; batch sorted.
// ---------------------------------------------------------------------------
__global__ __launch_bounds__(256) void pool3_k(const float* __restrict__ ydot,
                                               const int* __restrict__ batch, float* __restrict__ y,
                                               int N, int G) {
    __shared__ float gacc[512];
    int t = threadIdx.x;
    if (G <= 512) {
        for (int g = t; g < 512; g += 256) gacc[g] = 0.f;
        __syncthreads();
        int n0 = blockIdx.x * 2048 + t * 8;
        int curg = -1;
        float accv = 0.f;
        for (int i = 0; i < 8; ++i) {
            int n = n0 + i;
            if (n < N) {
                float v = ydot[n];
                int g = batch[n];
                if (g == curg) accv += v;
                else {
                    if (curg >= 0) atomicAdd(&gacc[curg], accv);
                    curg = g;
                    accv = v;
                }
            }
        }
        if (curg >= 0) atomicAdd(&gacc[curg], accv);
        __syncthreads();
        for (int g = t; g < G; g += 256) {
            float v = gacc[g];
            if (v != 0.f) atomicAdd(&y[g], v);
        }
    } else {
        int n0 = blockIdx.x * 2048 + t * 8;
        for (int i = 0; i < 8; ++i) {
            int n = n0 + i;
            if (n < N) atomicAdd(&y[batch[n]], ydot[n]);
        }
    }
}

// ---------------------------------------------------------------------------
// Launch
// ---------------------------------------------------------------------------
static inline size_t align256(size_t x) { return (x + 255) & ~(size_t)255; }

extern "C" void kernel_launch(void* const* d_in, const int* in_sizes, int n_in,
                              void* d_out, int out_size, void* d_ws, size_t ws_size,
                              hipStream_t stream) {
    const float* x0    = (const float*)d_in[0];
    const int*   eiA   = (const int*)d_in[1];
    const int*   eiB   = (const int*)d_in[2];
    const int*   batch = (const int*)d_in[3];
    const float* W[3]   = {(const float*)d_in[4],  (const float*)d_in[8],  (const float*)d_in[12]};
    const float* as_[3] = {(const float*)d_in[5],  (const float*)d_in[9],  (const float*)d_in[13]};
    const float* ad_[3] = {(const float*)d_in[6],  (const float*)d_in[10], (const float*)d_in[14]};
    const float* bb[3]  = {(const float*)d_in[7],  (const float*)d_in[11], (const float*)d_in[15]};
    const float* Wf = (const float*)d_in[16];
    const float* bf = (const float*)d_in[17];

    const int N = in_sizes[0] / 128;   // 50000 (< 65536: packed-pair assumption)
    const int E = in_sizes[1] / 2;
    const int G = out_size;
    float* y = (float*)d_out;

    const int nbkt = (N + 255) >> 8;

    char* p = (char*)d_ws;
    int2* rp2   = (int2*)p; p += align256((size_t)2 * N * 8);
    int* bktCnt = (int*)p;  p += align256((size_t)2 * nbkt * 4);
    int* cursors = (int*)p; p += 256;      // adjacent to bktCnt; zeroed by same memset
    int* colA   = (int*)p;  p += align256((size_t)E * 4);
    int* colB   = (int*)p;  p += align256((size_t)E * 4);
    _Float16* h16 = (_Float16*)p; p += align256((size_t)N * 64 * 2);
    float* es   = (float*)p; p += align256((size_t)N * 4);
    float* ed   = (float*)p; p += align256((size_t)N * 4);
    float* ydot = (float*)p; p += align256((size_t)N * 4);
    _Float16* Wt = (_Float16*)p; p += align256((size_t)3 * 8192 * 2);
    __half* xb0 = (__half*)p; p += align256((size_t)N * 128 * 2);
    __half* xb1 = (__half*)p; p += align256((size_t)N * 128 * 2);
    int* pairs = (int*)xb0;   // 2*nbkt*BCAP*4 ~ 14.5MB aliases xb0+xb1 (dead then)
    (void)ws_size; (void)n_in;

    const int KB = 256;
    const int WB = (N + 3) / 4;
    const int PB3 = (N + 2047) / 2048;

    // ---- CSR build via bucket sort (+fused W transpose, y init) ----
    hipMemsetAsync(bktCnt, 0, align256((size_t)2 * nbkt * 4) + 256, stream);
    bucket_k<<<2 * KB, 256, 0, stream>>>(eiA, eiB, E, nbkt, bktCnt, pairs, W[0], W[1], W[2], Wt, y, bf, G);
    bscat_k<<<2 * nbkt, 256, 0, stream>>>(bktCnt, pairs, N, nbkt, rp2, cursors, colA, colB);

    // ---- 3 GAT layers; weights shared between branches A and B ----
    const int GB = (N + 127) / 128;
    const int2* rp2A = rp2;
    const int2* rp2B = rp2 + N;
    gemm_k<0><<<GB, 256, 0, stream>>>(x0, Wt, as_[0], ad_[0], h16, es, ed, N);
    agg_k<0><<<WB, 256, 0, stream>>>(h16, es, ed, rp2A, colA, rp2B, colB, bb[0], xb0, N, Wf, ydot);
    gemm_k<1><<<GB, 256, 0, stream>>>(xb0, Wt + 8192, as_[1], ad_[1], h16, es, ed, N);
    agg_k<0><<<WB, 256, 0, stream>>>(h16, es, ed, rp2A, colA, rp2B, colB, bb[1], xb1, N, Wf, ydot);
    gemm_k<1><<<GB, 256, 0, stream>>>(xb1, Wt + 16384, as_[2], ad_[2], h16, es, ed, N);
    agg_k<1><<<WB, 256, 0, stream>>>(h16, es, ed, rp2A, colA, rp2B, colB, bb[2], (__half*)nullptr, N, Wf, ydot);

    // ---- tiny pool over ydot ----
    pool3_k<<<PB3, 256, 0, stream>>>(ydot, batch, y, N, G);
}